// Round 14
// baseline (824.291 us; speedup 1.0000x reference)
//
#include <hip/hip_runtime.h>

#define BB 256
#define LL 1024
#define TT 128
#define NTH 512
#define CH 64    // backward chunk rows staged in LDS
#define TTP 129  // padded row stride for transposed trans (kills bank conflicts)

typedef unsigned long long ull;

// LDS-only barrier: does NOT drain vmcnt, so in-flight global loads/stores
// stay outstanding across it.
__device__ __forceinline__ void lds_barrier() {
    asm volatile("s_waitcnt lgkmcnt(0)\n\ts_barrier" ::);
}

// Quad-local lane permute on the VALU (no LDS pipe, no barrier).
// 0xB1 = quad_perm [1,0,3,2] (XOR 1); 0x4E = quad_perm [2,3,0,1] (XOR 2).
template<int CTRL>
__device__ __forceinline__ float dpp_f(float v) {
    int r = __builtin_amdgcn_update_dpp(__float_as_int(v), __float_as_int(v),
                                        CTRL, 0xF, 0xF, false);
    return __int_as_float(r);
}

// Padded state index: +4 floats per 32 so the four quarter-segments start at
// bank offsets 0/4/8/12 (stride 36 floats) => the 4-address ds_read_b128
// (one address per quarter, 16-lane broadcast each) is bank-conflict-free
// (verified bank arithmetic, r4).
#define SP(i) ((i) + (((i) >> 5) << 2))

// ===================== workspace variant =====================
// Forward (r14): values-only + quad decomposition — the one untested cell.
//  thread (j = tid>>2 tag, q = tid&3 quarter), 512 thr / 8 waves (2/SIMD).
//  Phase 1 reads the double-buffered padded state (4-addr broadcast b128,
//  conflict-free), 32 add+fmax, 3-fmax residue merge, then TWO DPP quad
//  fmax merges (exact, order-independent — values need no tie-break).
//  q==0 lane commits m_t to ws and state to the OTHER buffer. ONE barrier.
//  This removes the pv LDS round-trip + one barrier (vs r8) without the
//  index-chain VALU that sank r4 and with 8 waves kept (vs r6's 4).
// Backward: r8's proven exact recovery (bit-exact recompute + ballot
//  first-match == jnp.argmax first-index), bm/bx staging, tT reads.
struct alignas(16) FwdSmem {
    float st[2][144];         // double-buffered padded Viterbi state
    unsigned char tags[LL];   // decoded tags staging
};

__global__ __launch_bounds__(NTH)
void viterbi_ws_kernel(const float* __restrict__ x,
                       const int* __restrict__ lengths,
                       const float* __restrict__ trans,
                       int* __restrict__ out,
                       float* __restrict__ ws) {
    __shared__ FwdSmem sm;
    extern __shared__ float dyn[];            // tT[TTP*TT] | bm[CH*TT] | bx[CH*TT]
    float* tT = dyn;                          // tT[c*TTP + i] = trans[i*TT + c]
    float* bm = dyn + TTP * TT;               // staged m-history rows
    float* bx = bm + CH * TT;                 // staged x rows

    const int b   = blockIdx.x;
    const int tid = threadIdx.x;
    const int j   = tid >> 2;    // tag column 0..127
    const int q   = tid & 3;     // predecessor quarter: i in [32q, 32q+32)
    const int l   = tid & 63;    // lane (used by epilogue/backward)

    int lenb = lengths[b];
    if (lenb < 1) lenb = 1;
    if (lenb > LL) lenb = LL;

    // Register-cache trans column slice: tc[ii] = trans[32q+ii][j]; pin.
    float tc[32];
    #pragma unroll
    for (int ii = 0; ii < 32; ++ii)
        tc[ii] = trans[(q * 32 + ii) * TT + j];
    #pragma unroll
    for (int ii = 0; ii < 32; ++ii)
        asm volatile("" : "+v"(tc[ii]));

    // Transposed trans in LDS for the backward pass — padded stride TTP=129.
    // 512-thread mapping: q2 = tid>>7 in 0..3, 32 rows each.
    {
        const int jj = tid & (TT - 1);
        const int q2 = tid >> 7;
        #pragma unroll
        for (int ii = 0; ii < 32; ++ii) {
            int r = q2 * 32 + ii;
            tT[jj * TTP + r] = trans[r * TT + jj];
        }
    }

    const float* xb  = x  + (size_t)b * LL * TT;
    float*       wsb = ws + (size_t)b * LL * TT;

    // row 0 of history := state_0 = x[0,:]
    if (tid < TT) { float v = xb[tid]; sm.st[0][SP(tid)] = v; wsb[tid] = v; }

    // Emission prefetch (only the q==0 lane of each quad consumes it).
    float xv = 0.0f;
    if (q == 0 && lenb > 1) xv = xb[TT + j];
    lds_barrier();

    // ---------------- forward (values only, ONE barrier/step) ----------------
    int p = 0;
    for (int t = 1; t < lenb; ++t) {
        // prefetch next step's emission (clamped; in flight across barrier)
        float xn = 0.0f;
        if (q == 0) {
            int tn = (t + 1 < lenb) ? (t + 1) : (lenb - 1);
            xn = xb[tn * TT + j];
        }

        // scan 32 predecessors: score = state[i] + trans[i][j]
        const float4* st4 = reinterpret_cast<const float4*>(&sm.st[p][q * 36]);
        float m0 = -3.4e38f, m1 = -3.4e38f, m2 = -3.4e38f, m3 = -3.4e38f;
        #pragma unroll
        for (int k = 0; k < 8; ++k) {
            float4 sv = st4[k];               // 4 addrs/wave, 16-lane broadcast
            m0 = fmaxf(m0, sv.x + tc[4 * k + 0]);
            m1 = fmaxf(m1, sv.y + tc[4 * k + 1]);
            m2 = fmaxf(m2, sv.z + tc[4 * k + 2]);
            m3 = fmaxf(m3, sv.w + tc[4 * k + 3]);
        }
        float bb = fmaxf(fmaxf(m0, m1), fmaxf(m2, m3));
        // cross-quarter merge inside the quad: 2 DPP fmax (exact, orderless)
        bb = fmaxf(bb, dpp_f<0xB1>(bb));
        bb = fmaxf(bb, dpp_f<0x4E>(bb));

        // one lane per tag commits; write goes to the OTHER state buffer, so
        // it cannot race this iteration's reads (single barrier suffices:
        // st[p] is only overwritten at t+1, after all waves passed this
        // step's barrier, i.e. after they finished reading it).
        if (q == 0) {
            wsb[t * TT + j] = bb;             // m_t row (pre-emission max)
            sm.st[p ^ 1][SP(j)] = bb + xv;
            xv = xn;
        }
        p ^= 1;
        lds_barrier();
    }

    // Drain our m-history stores and make them visible block-wide.
    __syncthreads();

    // ---- last_tag: exact first-index argmax over s_{len-1} (wave 0) ----
    // Recompute state = m + x from ws (bit-exact: same operands/order as
    // forward's st commit). Row 0 holds state_0 directly.
    int c = 0; float mv = 0.0f;
    if (tid < 64) {
        const float* mrow = wsb + (size_t)(lenb - 1) * TT;
        float s0, s1;
        if (lenb > 1) {
            s0 = mrow[l]      + xb[(lenb - 1) * TT + l];
            s1 = mrow[l + 64] + xb[(lenb - 1) * TT + l + 64];
        } else {
            s0 = mrow[l]; s1 = mrow[l + 64];
        }
        float mm = fmaxf(s0, s1);
        #pragma unroll
        for (int off = 1; off < 64; off <<= 1)
            mm = fmaxf(mm, __shfl_xor(mm, off));
        ull blo = __ballot(s0 == mm);         // lo half: indices 0..63 (first)
        if (blo) c = __ffsll(blo) - 1;
        else     c = 64 + __ffsll(__ballot(s1 == mm)) - 1;
        if (lenb > 1) mv = mrow[c];           // m_{len-1}[c]
    }

    // ---- chunked backward walk (r8 proven version; wave 0 walks) ----
    // Semantics (matches reference): tags[t] = c, THEN c = bp_t[c].
    int rhi = lenb - 2;                       // highest source row needed
    while (rhi >= 0) {
        int r0 = rhi - (CH - 1); if (r0 < 0) r0 = 0;
        int nrows = rhi - r0 + 1;
        const float4* wm4 = reinterpret_cast<const float4*>(wsb + r0 * TT);
        const float4* wx4 = reinterpret_cast<const float4*>(xb  + r0 * TT);
        float4* bm4 = reinterpret_cast<float4*>(bm);
        float4* bx4 = reinterpret_cast<float4*>(bx);
        int n4 = nrows * (TT / 4);
        for (int i4 = tid; i4 < n4; i4 += NTH) {
            bm4[i4] = wm4[i4];
            float4 v = wx4[i4];
            // row 0 holds state_0 directly: no emission re-add
            if (r0 == 0 && i4 < TT / 4) { v.x = 0.f; v.y = 0.f; v.z = 0.f; v.w = 0.f; }
            bx4[i4] = v;
        }
        lds_barrier();
        if (tid < 64) {
            for (int tt = r0 + nrows; tt >= r0 + 1; --tt) {
                int row = (tt - 1 - r0) * TT;
                // bit-exact recompute of forward scores:
                // state_{t-1}[i] = m + x (same operands/order as forward)
                float slo = (bm[row + l]      + bx[row + l])      + tT[c * TTP + l];
                float shi = (bm[row + 64 + l] + bx[row + 64 + l]) + tT[c * TTP + 64 + l];
                ull blo = __ballot(slo == mv);
                int nc;
                if (blo) nc = __ffsll(blo) - 1;              // first i in 0..63
                else     nc = 64 + __ffsll(__ballot(shi == mv)) - 1;
                if (l == 0) sm.tags[tt] = (unsigned char)c;  // CURRENT tag at tt
                c = nc;                                      // tag at tt-1
                mv = bm[row + c];             // m_{tt-1}[c] for next step
            }
        }
        lds_barrier();                        // protect bm/bx before reload
        rhi = r0 - 1;
    }
    if (tid == 0) sm.tags[0] = (unsigned char)c;
    lds_barrier();

    int* outb = out + (size_t)b * LL;
    for (int tt = tid; tt < LL; tt += NTH)
        outb[tt] = (tt < lenb) ? (int)sm.tags[tt] : 0;
}

// ===================== fallback (no workspace): round-0 kernel =====================
struct SmallSmem {
    float state[TT];
    float pv[NTH];
    int   pi[NTH];
    unsigned char tags[LL];
};

__global__ __launch_bounds__(NTH)
void viterbi_kernel(const float* __restrict__ x,
                    const int* __restrict__ lengths,
                    const float* __restrict__ trans,
                    int* __restrict__ out) {
    __shared__ SmallSmem sm;
    extern __shared__ unsigned char bp[];   // LL*TT bytes

    const int b   = blockIdx.x;
    const int tid = threadIdx.x;
    const int j   = tid & (TT - 1);
    const int q   = tid >> 7;

    int lenb = lengths[b];
    if (lenb < 1) lenb = 1;
    if (lenb > LL) lenb = LL;

    float tc[32];
    #pragma unroll
    for (int ii = 0; ii < 32; ++ii)
        tc[ii] = trans[(q * 32 + ii) * TT + j];

    const float* xb = x + (size_t)b * LL * TT;
    if (tid < TT) sm.state[tid] = xb[tid];

    float xv_cur = 0.0f, xv_next = 0.0f;
    if (tid < TT && lenb > 1) xv_cur = xb[TT + j];
    lds_barrier();

    for (int t = 1; t < lenb; ++t) {
        if (tid < TT) {
            int tn = (t + 1 < lenb) ? (t + 1) : (lenb - 1);
            xv_next = xb[tn * TT + j];
        }
        float best0 = -3.4e38f, best1 = -3.4e38f, best2 = -3.4e38f, best3 = -3.4e38f;
        int   bi0 = 0, bi1 = 1, bi2 = 2, bi3 = 3;
        const float4* st4 = reinterpret_cast<const float4*>(sm.state + q * 32);
        #pragma unroll
        for (int kk = 0; kk < 8; ++kk) {
            float4 sv = st4[kk];
            float s0 = sv.x + tc[4 * kk + 0];
            float s1 = sv.y + tc[4 * kk + 1];
            float s2 = sv.z + tc[4 * kk + 2];
            float s3 = sv.w + tc[4 * kk + 3];
            if (s0 > best0) { best0 = s0; bi0 = 4 * kk + 0; }
            if (s1 > best1) { best1 = s1; bi1 = 4 * kk + 1; }
            if (s2 > best2) { best2 = s2; bi2 = 4 * kk + 2; }
            if (s3 > best3) { best3 = s3; bi3 = 4 * kk + 3; }
        }
        float bb = best0; int bi = bi0;
        if (best1 > bb || (best1 == bb && bi1 < bi)) { bb = best1; bi = bi1; }
        if (best2 > bb || (best2 == bb && bi2 < bi)) { bb = best2; bi = bi2; }
        if (best3 > bb || (best3 == bb && bi3 < bi)) { bb = best3; bi = bi3; }
        sm.pv[tid] = bb;
        sm.pi[tid] = bi + q * 32;
        lds_barrier();

        if (tid < TT) {
            float bv = sm.pv[j];       int ix = sm.pi[j];
            float v1 = sm.pv[j + 128]; int i1 = sm.pi[j + 128];
            float v2 = sm.pv[j + 256]; int i2 = sm.pi[j + 256];
            float v3 = sm.pv[j + 384]; int i3 = sm.pi[j + 384];
            if (v1 > bv) { bv = v1; ix = i1; }
            if (v2 > bv) { bv = v2; ix = i2; }
            if (v3 > bv) { bv = v3; ix = i3; }
            sm.state[j] = bv + xv_cur;
            bp[t * TT + j] = (unsigned char)ix;
            xv_cur = xv_next;
        }
        lds_barrier();
    }

    if (tid == 0) {
        float bv = sm.state[0]; int ix = 0;
        for (int i = 1; i < TT; ++i) {
            float v = sm.state[i];
            if (v > bv) { bv = v; ix = i; }
        }
        int carry = ix;
        for (int t = lenb - 1; t >= 1; --t) {
            sm.tags[t] = (unsigned char)carry;
            carry = bp[t * TT + carry];
        }
        sm.tags[0] = (unsigned char)carry;
    }
    lds_barrier();

    int* outb = out + (size_t)b * LL;
    for (int t = tid; t < LL; t += NTH)
        outb[t] = (t < lenb) ? (int)sm.tags[t] : 0;
}

extern "C" void kernel_launch(void* const* d_in, const int* in_sizes, int n_in,
                              void* d_out, int out_size, void* d_ws, size_t ws_size,
                              hipStream_t stream) {
    const float* x       = (const float*)d_in[0];
    const int*   lengths = (const int*)d_in[1];
    // d_in[2] = tags (unused by decode)
    const float* trans   = (const float*)d_in[3];
    int*         out     = (int*)d_out;

    const size_t ws_needed = (size_t)BB * LL * TT * sizeof(float);  // 134 MB

    if (d_ws != nullptr && ws_size >= ws_needed) {
        // tT (padded, 64.5 KB) + bm/bx staging (64 KB) dynamic; ~2.2 KB static
        const int dyn = (TTP * TT + 2 * CH * TT) * (int)sizeof(float);  // 131584
        hipFuncSetAttribute((const void*)&viterbi_ws_kernel,
                            hipFuncAttributeMaxDynamicSharedMemorySize, dyn);
        viterbi_ws_kernel<<<BB, NTH, dyn, stream>>>(x, lengths, trans, out,
                                                    (float*)d_ws);
    } else {
        const int dyn = LL * TT;  // 131072 bytes of backpointers
        hipFuncSetAttribute((const void*)&viterbi_kernel,
                            hipFuncAttributeMaxDynamicSharedMemorySize, dyn);
        viterbi_kernel<<<BB, NTH, dyn, stream>>>(x, lengths, trans, out);
    }
}

// Round 15
// 764.942 us; speedup vs baseline: 1.0776x; 1.0776x over previous
//
#include <hip/hip_runtime.h>

#define BB 256
#define LL 1024
#define TT 128
#define NTH 512
#define CH 64    // backward chunk rows staged in LDS
#define TTP 129  // padded row stride for transposed trans (kills bank conflicts)

typedef unsigned long long ull;

// LDS-only barrier: does NOT drain vmcnt, so in-flight global loads/stores
// stay outstanding across it.
__device__ __forceinline__ void lds_barrier() {
    asm volatile("s_waitcnt lgkmcnt(0)\n\ts_barrier" ::);
}

// ===================== workspace variant =====================
// SESSION-BEST kernel (r8, measured 622us dispatch / 764us bench).
// Forward: values-only Viterbi (no argmax bookkeeping), 2-phase reduce with
// wave-uniform broadcast state reads, tc[] pinned in VGPRs. Per step t the
// pre-emission max row m_t goes to workspace.
// Backward: exact backpointer recovery via bit-exact score recompute +
// ballot first-match (== jnp.argmax first-index semantics, even under ties).
//
// Structural-ceiling evidence (r3-r14): nine forward topologies spanning
// barrier count {1,2}, reduce {funnel, DPP-quad, DPP-pair, self-serve,
// SGPR+readlane}, waves {4,8}, LDS traffic {32..82 instr/step} all land in
// 622-757us. The ~1200 cyc/step is a block-wide all-to-all-reduce latency
// floor (VALU 15%, HBM 3%, conflicts 0, occupancy LDS-capped) — not
// addressable by topology. Time-parallel scan costs 128x work (max-plus
// matmat) vs ~30x compute headroom; 2-step fusion exceeds register reach.
struct FwdSmem {
    float state[TT];          // current Viterbi state
    float pv[NTH];            // per-thread partial maxes
    unsigned char tags[LL];   // decoded tags staging
};

__global__ __launch_bounds__(NTH)
void viterbi_ws_kernel(const float* __restrict__ x,
                       const int* __restrict__ lengths,
                       const float* __restrict__ trans,
                       int* __restrict__ out,
                       float* __restrict__ ws) {
    __shared__ FwdSmem sm;
    extern __shared__ float dyn[];            // tT[TTP*TT] | bm[CH*TT] | bx[CH*TT]
    float* tT = dyn;                          // tT[c*TTP + i] = trans[i*TT + c]
    float* bm = dyn + TTP * TT;               // staged m-history rows
    float* bx = bm + CH * TT;                 // staged x rows

    const int b   = blockIdx.x;
    const int tid = threadIdx.x;
    const int j   = tid & (TT - 1);   // tag column
    const int q   = tid >> 7;         // predecessor quarter

    int lenb = lengths[b];
    if (lenb < 1) lenb = 1;
    if (lenb > LL) lenb = LL;

    // Register-cache trans column slice: tc[ii] = trans[32q+ii][j]; pin.
    float tc[32];
    #pragma unroll
    for (int ii = 0; ii < 32; ++ii)
        tc[ii] = trans[(q * 32 + ii) * TT + j];
    #pragma unroll
    for (int ii = 0; ii < 32; ++ii)
        asm volatile("" : "+v"(tc[ii]));

    // Transposed trans in LDS for the backward pass — padded stride TTP=129:
    // lanes write bank (j + r) % 32 -> 2-way (free). Re-read is L2-hot.
    #pragma unroll
    for (int ii = 0; ii < 32; ++ii) {
        int r = q * 32 + ii;
        tT[j * TTP + r] = trans[r * TT + j];
    }

    const float* xb  = x  + (size_t)b * LL * TT;
    float*       wsb = ws + (size_t)b * LL * TT;

    // row 0 of history := state_0 = x[0,:]
    if (tid < TT) { float v = xb[tid]; sm.state[tid] = v; wsb[tid] = v; }

    float xv = 0.0f, xn = 0.0f;
    if (tid < TT && lenb > 1) xv = xb[TT + j];
    lds_barrier();

    // ---------------- forward (values only) ----------------
    for (int t = 1; t < lenb; ++t) {
        if (tid < TT) {
            int tn = (t + 1 < lenb) ? (t + 1) : (lenb - 1);
            xn = xb[tn * TT + j];             // in flight across barriers
        }
        const float4* st4 = reinterpret_cast<const float4*>(sm.state + q * 32);
        float m0 = -3.4e38f, m1 = -3.4e38f, m2 = -3.4e38f, m3 = -3.4e38f;
        #pragma unroll
        for (int k = 0; k < 8; ++k) {
            float4 sv = st4[k];               // wave-uniform broadcast b128
            m0 = fmaxf(m0, sv.x + tc[4 * k + 0]);
            m1 = fmaxf(m1, sv.y + tc[4 * k + 1]);
            m2 = fmaxf(m2, sv.z + tc[4 * k + 2]);
            m3 = fmaxf(m3, sv.w + tc[4 * k + 3]);
        }
        sm.pv[tid] = fmaxf(fmaxf(m0, m1), fmaxf(m2, m3));
        lds_barrier();
        if (tid < TT) {
            float bv = fmaxf(fmaxf(sm.pv[j], sm.pv[j + 128]),
                             fmaxf(sm.pv[j + 256], sm.pv[j + 384]));
            wsb[t * TT + j] = bv;             // m_t row (pre-emission max)
            sm.state[j] = bv + xv;
            xv = xn;
        }
        lds_barrier();
    }

    // Drain our m-history stores and make them visible block-wide.
    __syncthreads();

    // ---- last_tag: exact first-index argmax over state (wave 0) ----
    int c = 0; float mv = 0.0f;
    const int l = tid;                        // lane id when tid < 64
    if (tid < 64) {
        float s0 = sm.state[l], s1 = sm.state[l + 64];
        float mm = fmaxf(s0, s1);
        #pragma unroll
        for (int off = 1; off < 64; off <<= 1)
            mm = fmaxf(mm, __shfl_xor(mm, off));
        ull blo = __ballot(s0 == mm);         // lo half: indices 0..63 (first)
        if (blo) c = __ffsll(blo) - 1;
        else     c = 64 + __ffsll(__ballot(s1 == mm)) - 1;
        if (lenb > 1) mv = wsb[(lenb - 1) * TT + c];   // m_{len-1}[c]
    }

    // ---- chunked backward walk (wave 0 walks; all threads stage) ----
    // Semantics (matches reference): tags[t] = c, THEN c = bp_t[c].
    int rhi = lenb - 2;                       // highest source row needed
    while (rhi >= 0) {
        int r0 = rhi - (CH - 1); if (r0 < 0) r0 = 0;
        int nrows = rhi - r0 + 1;
        const float4* wm4 = reinterpret_cast<const float4*>(wsb + r0 * TT);
        const float4* wx4 = reinterpret_cast<const float4*>(xb  + r0 * TT);
        float4* bm4 = reinterpret_cast<float4*>(bm);
        float4* bx4 = reinterpret_cast<float4*>(bx);
        int n4 = nrows * (TT / 4);
        for (int i4 = tid; i4 < n4; i4 += NTH) {
            bm4[i4] = wm4[i4];
            float4 v = wx4[i4];
            // row 0 holds state_0 directly: no emission re-add
            if (r0 == 0 && i4 < TT / 4) { v.x = 0.f; v.y = 0.f; v.z = 0.f; v.w = 0.f; }
            bx4[i4] = v;
        }
        lds_barrier();
        if (tid < 64) {
            for (int tt = r0 + nrows; tt >= r0 + 1; --tt) {
                int row = (tt - 1 - r0) * TT;
                // bit-exact recompute of forward scores:
                // state_{t-1}[i] = m + x (same operands/order as forward)
                float slo = (bm[row + l]      + bx[row + l])      + tT[c * TTP + l];
                float shi = (bm[row + 64 + l] + bx[row + 64 + l]) + tT[c * TTP + 64 + l];
                ull blo = __ballot(slo == mv);
                int nc;
                if (blo) nc = __ffsll(blo) - 1;              // first i in 0..63
                else     nc = 64 + __ffsll(__ballot(shi == mv)) - 1;
                if (l == 0) sm.tags[tt] = (unsigned char)c;  // CURRENT tag at tt
                c = nc;                                      // tag at tt-1
                mv = bm[row + c];             // m_{tt-1}[c] for next step
            }
        }
        lds_barrier();                        // protect bm/bx before reload
        rhi = r0 - 1;
    }
    if (tid == 0) sm.tags[0] = (unsigned char)c;
    lds_barrier();

    int* outb = out + (size_t)b * LL;
    for (int tt = tid; tt < LL; tt += NTH)
        outb[tt] = (tt < lenb) ? (int)sm.tags[tt] : 0;
}

// ===================== fallback (no workspace): round-0 kernel =====================
struct SmallSmem {
    float state[TT];
    float pv[NTH];
    int   pi[NTH];
    unsigned char tags[LL];
};

__global__ __launch_bounds__(NTH)
void viterbi_kernel(const float* __restrict__ x,
                    const int* __restrict__ lengths,
                    const float* __restrict__ trans,
                    int* __restrict__ out) {
    __shared__ SmallSmem sm;
    extern __shared__ unsigned char bp[];   // LL*TT bytes

    const int b   = blockIdx.x;
    const int tid = threadIdx.x;
    const int j   = tid & (TT - 1);
    const int q   = tid >> 7;

    int lenb = lengths[b];
    if (lenb < 1) lenb = 1;
    if (lenb > LL) lenb = LL;

    float tc[32];
    #pragma unroll
    for (int ii = 0; ii < 32; ++ii)
        tc[ii] = trans[(q * 32 + ii) * TT + j];
    #pragma unroll
    for (int ii = 0; ii < 32; ++ii)
        asm volatile("" : "+v"(tc[ii]));

    const float* xb = x + (size_t)b * LL * TT;
    if (tid < TT) sm.state[tid] = xb[tid];

    float xv_cur = 0.0f, xv_next = 0.0f;
    if (tid < TT && lenb > 1) xv_cur = xb[TT + j];
    lds_barrier();

    for (int t = 1; t < lenb; ++t) {
        if (tid < TT) {
            int tn = (t + 1 < lenb) ? (t + 1) : (lenb - 1);
            xv_next = xb[tn * TT + j];
        }
        float best0 = -3.4e38f, best1 = -3.4e38f, best2 = -3.4e38f, best3 = -3.4e38f;
        int   bi0 = 0, bi1 = 1, bi2 = 2, bi3 = 3;
        const float4* st4 = reinterpret_cast<const float4*>(sm.state + q * 32);
        #pragma unroll
        for (int k = 0; k < 8; ++k) {
            float4 sv = st4[k];
            float s0 = sv.x + tc[4 * k + 0];
            float s1 = sv.y + tc[4 * k + 1];
            float s2 = sv.z + tc[4 * k + 2];
            float s3 = sv.w + tc[4 * k + 3];
            if (s0 > best0) { best0 = s0; bi0 = 4 * k + 0; }
            if (s1 > best1) { best1 = s1; bi1 = 4 * k + 1; }
            if (s2 > best2) { best2 = s2; bi2 = 4 * k + 2; }
            if (s3 > best3) { best3 = s3; bi3 = 4 * k + 3; }
        }
        float bb = best0; int bi = bi0;
        if (best1 > bb || (best1 == bb && bi1 < bi)) { bb = best1; bi = bi1; }
        if (best2 > bb || (best2 == bb && bi2 < bi)) { bb = best2; bi = bi2; }
        if (best3 > bb || (best3 == bb && bi3 < bi)) { bb = best3; bi = bi3; }
        sm.pv[tid] = bb;
        sm.pi[tid] = bi + q * 32;
        lds_barrier();

        if (tid < TT) {
            float bv = sm.pv[j];       int ix = sm.pi[j];
            float v1 = sm.pv[j + 128]; int i1 = sm.pi[j + 128];
            float v2 = sm.pv[j + 256]; int i2 = sm.pi[j + 256];
            float v3 = sm.pv[j + 384]; int i3 = sm.pi[j + 384];
            if (v1 > bv) { bv = v1; ix = i1; }
            if (v2 > bv) { bv = v2; ix = i2; }
            if (v3 > bv) { bv = v3; ix = i3; }
            sm.state[j] = bv + xv_cur;
            bp[t * TT + j] = (unsigned char)ix;
            xv_cur = xv_next;
        }
        lds_barrier();
    }

    if (tid == 0) {
        float bv = sm.state[0]; int ix = 0;
        for (int i = 1; i < TT; ++i) {
            float v = sm.state[i];
            if (v > bv) { bv = v; ix = i; }
        }
        int carry = ix;
        for (int t = lenb - 1; t >= 1; --t) {
            sm.tags[t] = (unsigned char)carry;
            carry = bp[t * TT + carry];
        }
        sm.tags[0] = (unsigned char)carry;
    }
    lds_barrier();

    int* outb = out + (size_t)b * LL;
    for (int t = tid; t < LL; t += NTH)
        outb[t] = (t < lenb) ? (int)sm.tags[t] : 0;
}

extern "C" void kernel_launch(void* const* d_in, const int* in_sizes, int n_in,
                              void* d_out, int out_size, void* d_ws, size_t ws_size,
                              hipStream_t stream) {
    const float* x       = (const float*)d_in[0];
    const int*   lengths = (const int*)d_in[1];
    // d_in[2] = tags (unused by decode)
    const float* trans   = (const float*)d_in[3];
    int*         out     = (int*)d_out;

    const size_t ws_needed = (size_t)BB * LL * TT * sizeof(float);  // 134 MB

    if (d_ws != nullptr && ws_size >= ws_needed) {
        // tT (padded, 64.5 KB) + bm/bx staging (64 KB) dynamic; ~3.6 KB static
        const int dyn = (TTP * TT + 2 * CH * TT) * (int)sizeof(float);  // 131584
        hipFuncSetAttribute((const void*)&viterbi_ws_kernel,
                            hipFuncAttributeMaxDynamicSharedMemorySize, dyn);
        viterbi_ws_kernel<<<BB, NTH, dyn, stream>>>(x, lengths, trans, out,
                                                    (float*)d_ws);
    } else {
        const int dyn = LL * TT;  // 131072 bytes of backpointers
        hipFuncSetAttribute((const void*)&viterbi_kernel,
                            hipFuncAttributeMaxDynamicSharedMemorySize, dyn);
        viterbi_kernel<<<BB, NTH, dyn, stream>>>(x, lengths, trans, out);
    }
}